// Round 1
// 3024.694 us; speedup vs baseline: 2.2598x; 2.2598x over previous
//
#include <hip/hip_runtime.h>
#include <math.h>

#define N 64
#define LDC 68            // col-major leading dim (floats); bank stride = 4 words
                          //  -> 8 consecutive tournament p's hit 8 distinct bank bases
#define MAX_SWEEPS 10     // with early exit; typical matrices converge in ~5-6
#define SKIP_TOL2 9e-12f  // skip rotation if gamma^2 <= tol2 * a * b  (|g| <= 3e-6 * sp*sq)

__device__ __forceinline__ void get_pair(int r, int k, int& p, int& q) {
    // Circle-method tournament: round r in [0,63), pair k in [0,32)
    if (k == 0) { p = 63; q = r; }
    else {
        p = r + k; if (p >= 63) p -= 63;
        q = r - k; if (q < 0)  q += 63;
    }
}

// VALU-pipe cross-lane add via DPP (replaces ds_swizzle-based __shfl_xor).
// 0xB1 = quad_perm [1,0,3,2] (xor1), 0x4E = quad_perm [2,3,0,1] (xor2),
// 0x141 = row_half_mirror (maps across the two quads of each 8-lane group;
// valid here because after xor1+xor2 the value is uniform within each quad).
template <int CTRL>
__device__ __forceinline__ float dpp_add(float x) {
    int m = __builtin_amdgcn_update_dpp(0, __float_as_int(x), CTRL, 0xF, 0xF, true);
    return x + __int_as_float(m);
}

__global__ __launch_bounds__(256)
void logeig_kernel(const float* __restrict__ P, float* __restrict__ Out) {
    __shared__ float As[N * LDC];   // column-major: As[c*LDC + i] = elem (row i, col c)
    __shared__ float nrm[N];        // running ||col||^2 (Gram diagonal)
    __shared__ float lw[N];         // log(lambda)/lambda
    __shared__ int notconv;

    const int t = threadIdx.x;
    const int bid = blockIdx.x;
    const float* A0 = P + (size_t)bid * (N * N);
    float* O = Out + (size_t)bid * (N * N);

    // ---- Load P. P is symmetric, so column c (col-major) = row c of P:
    // contiguous global float4 -> contiguous LDS float4, fully coalesced.
    {
        const float4* A4 = (const float4*)A0;
        #pragma unroll
        for (int kk = 0; kk < 4; ++kk) {
            int f = t + kk * 256;           // float4 index in [0,1024)
            float4 v = A4[f];
            int e = f << 2;
            int r = e >> 6;                 // row of P = dest column
            int i = e & 63;
            *(float4*)&As[r * LDC + i] = v;
        }
    }
    __syncthreads();

    // ---- Cholesky P = L L^T, in place, lower triangle (i >= c) in col-major.
    for (int k = 0; k < N; ++k) {
        if (t == 0) As[k * LDC + k] = sqrtf(fmaxf(As[k * LDC + k], 1e-20f));
        __syncthreads();
        {
            float dinv = 1.0f / As[k * LDC + k];
            for (int i = k + 1 + t; i < N; i += 256) As[k * LDC + i] *= dinv;
        }
        __syncthreads();
        // trailing update: A[i][j] -= L[i][k]*L[j][k], j>k, i>=j
        for (int j = k + 1 + (t >> 3); j < N; j += 32) {
            float ljk = As[k * LDC + j];
            for (int i = j + (t & 7); i < N; i += 8)
                As[j * LDC + i] = fmaf(-As[k * LDC + i], ljk, As[j * LDC + i]);
        }
        __syncthreads();
    }

    // ---- zero strict upper triangle (still holds P entries), init column norms
    for (int f = t; f < N * N; f += 256) {
        int c = f >> 6, i = f & 63;
        if (i < c) As[c * LDC + i] = 0.f;
    }
    __syncthreads();
    if (t < N) {
        float s = 0.f;
        const float* cc = &As[t * LDC];
        for (int i = 0; i < N; ++i) { float x = cc[i]; s = fmaf(x, x, s); }
        nrm[t] = s;
    }
    __syncthreads();

    // ---- One-sided Jacobi on the columns of L.
    // Pair k handled by 8 lanes (g = t&7), each owning 8 rows -> all b128 LDS ops.
    // Round pairs partition the 64 columns => ONE barrier per round suffices.
    const int kp = t >> 3;    // pair index 0..31
    const int g  = t & 7;     // sub-lane within pair
    int conv = 0;
    for (int sweep = 0; sweep < MAX_SWEEPS && !conv; ++sweep) {
        if (t == 0) notconv = 0;
        __syncthreads();
        for (int r = 0; r < 63; ++r) {
            int p, q; get_pair(r, kp, p, q);
            float* cp = &As[p * LDC + (g << 3)];
            float* cq = &As[q * LDC + (g << 3)];
            float4 ap0 = *(float4*)cp;
            float4 ap1 = *(float4*)(cp + 4);
            float4 aq0 = *(float4*)cq;
            float4 aq1 = *(float4*)(cq + 4);
            // gamma = col_p . col_q  (partial over my 8 rows, then 8-lane DPP reduce)
            float gd = ap0.x * aq0.x;
            gd = fmaf(ap0.y, aq0.y, gd);
            gd = fmaf(ap0.z, aq0.z, gd);
            gd = fmaf(ap0.w, aq0.w, gd);
            gd = fmaf(ap1.x, aq1.x, gd);
            gd = fmaf(ap1.y, aq1.y, gd);
            gd = fmaf(ap1.z, aq1.z, gd);
            gd = fmaf(ap1.w, aq1.w, gd);
            gd = dpp_add<0xB1>(gd);
            gd = dpp_add<0x4E>(gd);
            gd = dpp_add<0x141>(gd);
            float a = nrm[p], b = nrm[q];
            if (gd * gd > SKIP_TOL2 * a * b) {
                // Jacobi rotation zeroing off-diag of Gram 2x2 [[a,g],[g,b]]
                float tau = (b - a) / (2.f * gd);
                float tt = 1.f / (fabsf(tau) + sqrtf(fmaf(tau, tau, 1.f)));
                if (tau < 0.f) tt = -tt;
                float c = rsqrtf(fmaf(tt, tt, 1.f));
                float s = tt * c;
                float4 np0, np1, nq0, nq1;
                np0.x = c * ap0.x - s * aq0.x;  nq0.x = s * ap0.x + c * aq0.x;
                np0.y = c * ap0.y - s * aq0.y;  nq0.y = s * ap0.y + c * aq0.y;
                np0.z = c * ap0.z - s * aq0.z;  nq0.z = s * ap0.z + c * aq0.z;
                np0.w = c * ap0.w - s * aq0.w;  nq0.w = s * ap0.w + c * aq0.w;
                np1.x = c * ap1.x - s * aq1.x;  nq1.x = s * ap1.x + c * aq1.x;
                np1.y = c * ap1.y - s * aq1.y;  nq1.y = s * ap1.y + c * aq1.y;
                np1.z = c * ap1.z - s * aq1.z;  nq1.z = s * ap1.z + c * aq1.z;
                np1.w = c * ap1.w - s * aq1.w;  nq1.w = s * ap1.w + c * aq1.w;
                *(float4*)cp = np0;
                *(float4*)(cp + 4) = np1;
                *(float4*)cq = nq0;
                *(float4*)(cq + 4) = nq1;
                if (g == 0) {
                    // exact update identities: a' = a - t*g, b' = b + t*g
                    nrm[p] = a - tt * gd;
                    nrm[q] = b + tt * gd;
                    notconv = 1;
                }
            }
            __syncthreads();
        }
        conv = (notconv == 0);
        __syncthreads();   // protect flag reads from next sweep's reset
    }

    // ---- eigen coefficients: column k = sigma_k * u_k, lambda = ||col||^2 (exact recompute)
    if (t < N) {
        float s = 0.f;
        const float* cc = &As[t * LDC];
        for (int i = 0; i < N; ++i) { float x = cc[i]; s = fmaf(x, x, s); }
        s = fmaxf(s, 1e-30f);
        lw[t] = logf(s) / s;   // X = sum_k (log l / l) c_k c_k^T
    }
    __syncthreads();

    // ---- X = sum_k lw[k] * c_k c_k^T ; 4x4 output tile per thread
    {
        int ti = t >> 4;
        int tj = t & 15;
        float acc[4][4];
        #pragma unroll
        for (int a2 = 0; a2 < 4; ++a2)
            #pragma unroll
            for (int b2 = 0; b2 < 4; ++b2) acc[a2][b2] = 0.f;

        for (int k = 0; k < N; ++k) {
            float w = lw[k];
            float4 ui = *(const float4*)&As[k * LDC + 4 * ti];
            float4 uj = *(const float4*)&As[k * LDC + 4 * tj];
            uj.x *= w; uj.y *= w; uj.z *= w; uj.w *= w;
            float ua[4] = {ui.x, ui.y, ui.z, ui.w};
            float ub[4] = {uj.x, uj.y, uj.z, uj.w};
            #pragma unroll
            for (int a2 = 0; a2 < 4; ++a2)
                #pragma unroll
                for (int b2 = 0; b2 < 4; ++b2)
                    acc[a2][b2] = fmaf(ua[a2], ub[b2], acc[a2][b2]);
        }
        #pragma unroll
        for (int a2 = 0; a2 < 4; ++a2) {
            float4 vout = make_float4(acc[a2][0], acc[a2][1], acc[a2][2], acc[a2][3]);
            ((float4*)O)[(4 * ti + a2) * 16 + tj] = vout;
        }
    }
}

extern "C" void kernel_launch(void* const* d_in, const int* in_sizes, int n_in,
                              void* d_out, int out_size, void* d_ws, size_t ws_size,
                              hipStream_t stream) {
    const float* P = (const float*)d_in[0];
    float* Out = (float*)d_out;
    int nmat = in_sizes[0] / (N * N);    // 8192
    logeig_kernel<<<dim3(nmat), dim3(256), 0, stream>>>(P, Out);
}